// Round 2
// baseline (1601.162 us; speedup 1.0000x reference)
//
#include <hip/hip_runtime.h>
#include <stdint.h>
#include <math.h>

// Problem constants (from reference)
#define T_STEPS 128
#define NB      128
#define HID     64
#define CONVOUT 4096
#define NSUB    5
#define SUBSZ   14      // A+B+C = 5+3+6
#define NG      90      // A*B*C
#define STATE   99
#define DIN     4111    // CONVOUT + 3*NSUB
#define WFCOLS  4125    // CONVOUT + 2*SUBSZ + 1
#define WBCOLS  4110    // CONVOUT + SUBSZ

// ---------------- Threefry-2x32 (JAX-compatible) ----------------
__device__ __forceinline__ void tf2x32(unsigned k0, unsigned k1,
                                       unsigned x0, unsigned x1,
                                       unsigned &o0, unsigned &o1) {
  unsigned K0 = k0, K1 = k1, K2 = k0 ^ k1 ^ 0x1BD11BDAu;
  x0 += K0; x1 += K1;
  const int R0[4] = {13, 15, 26, 6};
  const int R1[4] = {17, 29, 16, 24};
  #pragma unroll
  for (int j = 0; j < 4; ++j) { x0 += x1; x1 = (x1 << R0[j]) | (x1 >> (32 - R0[j])); x1 ^= x0; }
  x0 += K1; x1 += K2 + 1u;
  #pragma unroll
  for (int j = 0; j < 4; ++j) { x0 += x1; x1 = (x1 << R1[j]) | (x1 >> (32 - R1[j])); x1 ^= x0; }
  x0 += K2; x1 += K0 + 2u;
  #pragma unroll
  for (int j = 0; j < 4; ++j) { x0 += x1; x1 = (x1 << R0[j]) | (x1 >> (32 - R0[j])); x1 ^= x0; }
  x0 += K0; x1 += K1 + 3u;
  #pragma unroll
  for (int j = 0; j < 4; ++j) { x0 += x1; x1 = (x1 << R1[j]) | (x1 >> (32 - R1[j])); x1 ^= x0; }
  x0 += K1; x1 += K2 + 4u;
  #pragma unroll
  for (int j = 0; j < 4; ++j) { x0 += x1; x1 = (x1 << R0[j]) | (x1 >> (32 - R0[j])); x1 ^= x0; }
  x0 += K2; x1 += K0 + 5u;
  o0 = x0; o1 = x1;
}

// JAX uniform(minval=tiny32, maxval=1) -> gumbel, computed in FP64 to match
// the fp64 numpy reference's sampling margins to ~1e-16.
__device__ __forceinline__ double bits_to_gumbel_d(unsigned bits) {
  float f = __uint_as_float((bits >> 9) | 0x3f800000u) - 1.0f;   // exact in f32
  const double tiny = (double)1.17549435e-38f;
  double u = fmax(tiny, (double)f + tiny);
  return -log(-log(u));
}

__device__ __forceinline__ float rlane(float v, int l) {
  return __int_as_float(__builtin_amdgcn_readlane(__float_as_int(v), l));
}

// ---------------- K0: pack/transpose weights: Wt[k][68] = {Wf rows 0..63, Wb rows 0..1} ----------------
__global__ void k_transpose(const float* __restrict__ Wf, const float* __restrict__ Wb,
                            float* __restrict__ Wt) {
  int idx = blockIdx.x * 256 + threadIdx.x;     // idx < 66*4096
  int c = idx >> 12;                            // 0..65
  int k = idx & 4095;
  float v = (c < 64) ? Wf[(size_t)c * WFCOLS + k] : Wb[(size_t)(c - 64) * WBCOLS + k];
  Wt[(size_t)k * 68 + c] = v;
}

// ---------------- K1: big GEMM  Xf[row][64] (fp32), Xb[row][2] (FP64) ----------------
// 256 blocks x 256 threads: 64 rows/block, 4 k-slices (one per wave, wave-uniform -> s_load weights)
__global__ __launch_bounds__(256) void k_gemm(const float* __restrict__ inp,
                                              const float* __restrict__ Wt,
                                              float* __restrict__ Xf,
                                              double* __restrict__ Xb) {
  __shared__ float  red[2][64][65];
  __shared__ double redd[2][64][2];
  int tid = threadIdx.x;
  int r = tid & 63;
  int q = __builtin_amdgcn_readfirstlane(tid >> 6);   // wave-uniform k-slice id
  int row = blockIdx.x * 64 + r;
  const float* xrow  = inp + (size_t)row * DIN + q * 1024;
  const float* wbase = Wt + (size_t)q * 1024 * 68;

  float acc[64];
  double accd0 = 0.0, accd1 = 0.0;
  #pragma unroll
  for (int c = 0; c < 64; ++c) acc[c] = 0.f;

  for (int k = 0; k < 1024; ++k) {
    float x = xrow[k];
    const float* w = wbase + (size_t)k * 68;   // uniform address -> scalar loads
    #pragma unroll
    for (int c = 0; c < 64; ++c) acc[c] = fmaf(x, w[c], acc[c]);
    double xd = (double)x;
    accd0 = fma(xd, (double)w[64], accd0);
    accd1 = fma(xd, (double)w[65], accd1);
  }
  // tree-reduce the 4 k-slices
  if (q >= 2) {
    float* dst = red[q - 2][r];
    #pragma unroll
    for (int c = 0; c < 64; ++c) dst[c] = acc[c];
    redd[q - 2][r][0] = accd0; redd[q - 2][r][1] = accd1;
  }
  __syncthreads();
  if (q < 2) {
    const float* s = red[q][r];
    #pragma unroll
    for (int c = 0; c < 64; ++c) acc[c] += s[c];
    accd0 += redd[q][r][0]; accd1 += redd[q][r][1];
  }
  __syncthreads();
  if (q == 1) {
    float* dst = red[0][r];
    #pragma unroll
    for (int c = 0; c < 64; ++c) dst[c] = acc[c];
    redd[0][r][0] = accd0; redd[0][r][1] = accd1;
  }
  __syncthreads();
  if (q == 0) {
    const float* s = red[0][r];
    #pragma unroll
    for (int c = 0; c < 64; ++c) acc[c] += s[c];
    accd0 += redd[0][r][0]; accd1 += redd[0][r][1];
    #pragma unroll
    for (int c = 0; c < 64; ++c) Xf[(size_t)row * 64 + c] = acc[c];
    Xb[(size_t)row * 2 + 0] = accd0;
    Xb[(size_t)row * 2 + 1] = accd1;
  }
}

// ---------------- K2: gumbel noise (JAX partitionable threefry), FP64 ----------------
__global__ void k_noise(double* __restrict__ Gg, double* __restrict__ Gb) {
  int t = blockIdx.x, tid = threadIdx.x;
  unsigned a, b, k1a, k1b, k2a, k2b, o0, o1;
  tf2x32(0u, 42u, 0u, (unsigned)t, a, b);      // keys[t] = split(key(42),128)[t]
  tf2x32(a, b, 0u, 0u, k1a, k1b);              // k1
  tf2x32(a, b, 0u, 1u, k2a, k2b);              // k2
  for (int i = tid; i < NB * NG; i += 256) {
    tf2x32(k1a, k1b, 0u, (unsigned)i, o0, o1);
    Gg[(size_t)t * NB * NG + i] = bits_to_gumbel_d(o0 ^ o1);
  }
  {
    int i = tid;                               // NB*2 == 256 == blockDim
    tf2x32(k2a, k2b, 0u, (unsigned)i, o0, o1);
    Gb[(size_t)t * NB * 2 + i] = bits_to_gumbel_d(o0 ^ o1);
  }
}

// ---------------- K3: sequential scan, one block per batch row ----------------
__global__ __launch_bounds__(256) void k_scan(
    const float* __restrict__ inp, const float* __restrict__ hx,
    const float* __restrict__ Wf, const float* __restrict__ bf,
    const float* __restrict__ Wih, const float* __restrict__ bih,
    const float* __restrict__ bhh, const float* __restrict__ Wc,
    const float* __restrict__ bc, const float* __restrict__ Wl,
    const float* __restrict__ bl, const float* __restrict__ Wpi,
    const float* __restrict__ bpi, const float* __restrict__ Wb,
    const float* __restrict__ bb,
    const float* __restrict__ Xf, const double* __restrict__ Xb,
    const double* __restrict__ Gg, const double* __restrict__ Gb,
    float* __restrict__ out) {
  const int n = blockIdx.x;
  const int tid = threadIdx.x;
  const int lane = tid & 63;

  __shared__ float st[STATE];          // [p(5) r(14) h(64) g(14) b(1) lp(1)]
  __shared__ float s_arr[HID];
  __shared__ float gi_arr[192];
  __shared__ float pconv_arr[NSUB];
  __shared__ float Mt[NSUB][SUBSZ];
  __shared__ double lgbuf[NG];
  __shared__ double vbuf[NG];
  __shared__ float Wbs[2][SUBSZ];
  __shared__ float bb_s[2];
  __shared__ float wfs_sh[29][HID];    // Wf state columns, transposed [k][j]
  __shared__ float cg_sh;
  __shared__ double lpg_sh;
  __shared__ int gidx_sh, nz_sh;

  // ---- per-thread register-resident weights ----
  int m_ih = (tid < 192) ? tid : 191;
  float wih[128];
  #pragma unroll
  for (int k = 0; k < 128; ++k) wih[k] = Wih[(size_t)m_ih * 128 + k];
  float bih_r = bih[m_ih];
  int m_pi = (tid < NG) ? tid : 0;
  float wpi[78];
  #pragma unroll
  for (int k = 0; k < 78; ++k) wpi[k] = Wpi[(size_t)m_pi * 78 + k];
  float bpi_r = bpi[m_pi];
  float bf_r  = bf[lane];
  float bhr_r = bhh[lane], bhz_r = bhh[64 + lane], bhn_r = bhh[128 + lane];
  float wc0 = Wc[lane], wc1 = Wc[64 + lane], bc0 = bc[0];
  float wl0 = Wl[lane], wl1 = Wl[64 + lane], wl2 = Wl[128 + lane];
  float bl0 = bl[0], bl1 = bl[1], bl2 = bl[2];

  // ---- one-time setup ----
  if (tid == 0) nz_sh = 0;
  if (tid < 5) {
    const float* r0 = inp + (size_t)n * DIN + CONVOUT;
    int ttv  = (int)r0[tid];
    int cntv = (int)r0[5 + tid] - 1;
    int objv = (int)r0[10 + tid];
    #pragma unroll
    for (int s2 = 0; s2 < SUBSZ; ++s2) Mt[tid][s2] = 0.f;
    Mt[tid][ttv] = 1.f; Mt[tid][5 + cntv] = 1.f; Mt[tid][8 + objv] = 1.f;
  }
  if (tid < 28) Wbs[tid / 14][tid % 14] = Wb[(size_t)(tid / 14) * WBCOLS + CONVOUT + (tid % 14)];
  if (tid < 2) bb_s[tid] = bb[tid];
  for (int i = tid; i < 29 * 64; i += 256)
    wfs_sh[i >> 6][i & 63] = Wf[(size_t)(i & 63) * WFCOLS + CONVOUT + (i >> 6)];
  __syncthreads();
  int any = 0;
  for (int i = tid; i < NB * STATE; i += 256) any |= (hx[i] != 0.f);
  if (any) nz_sh = 1;
  if (tid < STATE) st[tid] = hx[(size_t)n * STATE + tid];
  __syncthreads();
  if (nz_sh == 0) {   // new episode init
    if (tid == 0) st[0] = 1.f;
    if (tid < SUBSZ) { st[5 + tid] = Mt[0][tid]; st[83 + tid] = Mt[0][tid]; }
  }
  float xf_cur = (tid < 64) ? Xf[(size_t)n * 64 + tid] : 0.f;
  float xf_next = 0.f;
  __syncthreads();

  const size_t out_final = (size_t)T_STEPS * NB * STATE;

  #pragma unroll 1
  for (int t = 0; t < T_STEPS; ++t) {
    // ---- phase A: s (wave0), l/softmax + pconv (wave1); prefetch noise ----
    double gum_g = (tid < NG) ? Gg[(size_t)t * NB * NG + n * NG + tid] : 0.0;
    double gb0 = 0.0, gb1 = 0.0, xb0 = 0.0, xb1 = 0.0;
    if (tid == 0) {
      gb0 = Gb[(size_t)t * NB * 2 + n * 2 + 0];
      gb1 = Gb[(size_t)t * NB * 2 + n * 2 + 1];
      xb0 = Xb[((size_t)t * NB + n) * 2 + 0];
      xb1 = Xb[((size_t)t * NB + n) * 2 + 1];
    }
    if (tid < 64) {
      // rgb = concat(r_, g_, bprev), one element per lane (lanes 0..28)
      float rgb = 0.f;
      if (lane < 14) rgb = st[5 + lane];
      else if (lane < 28) rgb = st[83 + (lane - 14)];
      else if (lane == 28) rgb = st[97];
      float acc = xf_cur + bf_r;
      #pragma unroll
      for (int k = 0; k < 29; ++k) acc = fmaf(wfs_sh[k][lane], rlane(rgb, k), acc);
      s_arr[lane] = acc;
    } else if (tid < 128) {
      float hprev = st[19 + lane];
      float p0 = wl0 * hprev, p1 = wl1 * hprev, p2 = wl2 * hprev;
      #pragma unroll
      for (int off = 32; off > 0; off >>= 1) {
        p0 += __shfl_xor(p0, off, 64); p1 += __shfl_xor(p1, off, 64); p2 += __shfl_xor(p2, off, 64);
      }
      p0 += bl0; p1 += bl1; p2 += bl2;
      float mx = fmaxf(p0, fmaxf(p1, p2));
      float e0 = expf(p0 - mx), e1 = expf(p1 - mx), e2 = expf(p2 - mx);
      float se = e0 + e1 + e2;
      float l0 = e0 / se, l1 = e1 / se, l2 = e2 / se;
      if (lane < 5) {
        float a = (lane >= 1) ? st[lane - 1] : 0.f;
        float b = st[lane];
        float c = (lane < 4) ? st[lane + 1] : 0.f;
        pconv_arr[lane] = a * l0 + b * l1 + c * l2;
      }
    }
    __syncthreads();   // bar1: s_arr, pconv ready

    // ---- phase B: gi (waves 0-2, weights in VGPR + readlane broadcast), cg (wave3) ----
    float s_reg = s_arr[lane];
    float h_reg = st[19 + lane];
    if (tid < 64) xf_next = Xf[(size_t)(((t < T_STEPS - 1) ? t + 1 : t) * NB + n) * 64 + lane];
    if (tid < 192) {
      float acc = bih_r;
      #pragma unroll
      for (int k = 0; k < 64; ++k) acc = fmaf(wih[k], rlane(s_reg, k), acc);
      #pragma unroll
      for (int k = 0; k < 64; ++k) acc = fmaf(wih[64 + k], rlane(h_reg, k), acc);
      gi_arr[tid] = acc;
    } else {
      float acc = fmaf(wc1, h_reg, wc0 * s_reg);
      #pragma unroll
      for (int off = 32; off > 0; off >>= 1) acc += __shfl_xor(acc, off, 64);
      float cg = 1.f / (1.f + expf(-(acc + bc0)));
      if (lane == 0) cg_sh = cg;
    }
    __syncthreads();   // bar2: gi_arr, cg ready

    float cg = cg_sh;
    // ---- phase C/D: gates + state updates (p, r, h) ----
    if (tid < 64) {
      float rg = 1.f / (1.f + expf(-(gi_arr[tid] + bhr_r)));
      float z  = 1.f / (1.f + expf(-(gi_arr[64 + tid] + bhz_r)));
      float nn = tanhf(gi_arr[128 + tid] + rg * bhn_r);
      float hnew = (1.f - z) * nn;
      st[19 + tid] = cg * hnew + (1.f - cg) * st[19 + tid];
    } else if (tid < 78) {
      int si = tid - 64;
      float rn = 0.f;
      #pragma unroll
      for (int k = 0; k < 5; ++k) rn = fmaf(pconv_arr[k], Mt[k][si], rn);
      st[5 + si] = cg * rn + (1.f - cg) * st[5 + si];
    } else if (tid < 83) {
      int j = tid - 78;
      st[j] = cg * pconv_arr[j] + (1.f - cg) * st[j];
    }
    __syncthreads();   // bar3: new h, r, p

    // ---- phase E: lg = [h,r] @ Wpi.T + bpi, FP64 accumulate (threads 0..89) ----
    float hr_lo = st[19 + lane];
    float hr_hi = (lane < 14) ? st[5 + lane] : 0.f;
    if (tid < NG) {
      double acc = (double)bpi_r;
      #pragma unroll
      for (int k = 0; k < 64; ++k) acc = fma((double)wpi[k], (double)rlane(hr_lo, k), acc);
      #pragma unroll
      for (int k = 0; k < 14; ++k) acc = fma((double)wpi[64 + k], (double)rlane(hr_hi, k), acc);
      lgbuf[tid] = acc;
      vbuf[tid] = acc + gum_g;    // same add as ref (gumbel + logits), commutative
    }
    __syncthreads();   // bar4

    // ---- phase F: argmax + log_softmax reductions, FP64 (wave0) ----
    if (tid < 64) {
      double a = vbuf[tid]; int ia = tid;
      if (tid + 64 < NG) { double b = vbuf[tid + 64]; if (b > a) { a = b; ia = tid + 64; } }
      #pragma unroll
      for (int off = 32; off > 0; off >>= 1) {
        double ob = __shfl_xor(a, off, 64);
        int    oi = __shfl_xor(ia, off, 64);
        if (ob > a || (ob == a && oi < ia)) { a = ob; ia = oi; }
      }
      double ml = lgbuf[tid]; if (tid + 64 < NG) ml = fmax(ml, lgbuf[tid + 64]);
      #pragma unroll
      for (int off = 32; off > 0; off >>= 1) ml = fmax(ml, __shfl_xor(ml, off, 64));
      double e = exp(lgbuf[tid] - ml) + ((tid + 64 < NG) ? exp(lgbuf[tid + 64] - ml) : 0.0);
      #pragma unroll
      for (int off = 32; off > 0; off >>= 1) e += __shfl_xor(e, off, 64);
      if (tid == 0) { gidx_sh = ia; lpg_sh = (lgbuf[ia] - ml) - log(e); }
    }
    __syncthreads();   // bar5

    // ---- phase G: g update from sampled embedding ----
    if (tid < SUBSZ) {
      int gidx = gidx_sh;
      int t1 = gidx / 18, rem = gidx - t1 * 18;
      int b1 = rem / 6, c1 = rem - b1 * 6;
      float ge;
      if (tid < 5)      ge = (tid == t1) ? 1.f : 0.f;
      else if (tid < 8) ge = ((tid - 5) == b1) ? 1.f : 0.f;
      else              ge = ((tid - 8) == c1) ? 1.f : 0.f;
      st[83 + tid] = cg * ge + (1.f - cg) * st[83 + tid];
    }
    __syncthreads();   // bar6: new g

    if (tid == 0) {
      double lb0 = xb0 + (double)bb_s[0], lb1 = xb1 + (double)bb_s[1];
      #pragma unroll
      for (int k = 0; k < SUBSZ; ++k) {
        double gv = (double)st[83 + k];
        lb0 = fma(gv, (double)Wbs[0][k], lb0);
        lb1 = fma(gv, (double)Wbs[1][k], lb1);
      }
      double v0 = lb0 + gb0, v1 = lb1 + gb1;
      int bi = (v1 > v0) ? 1 : 0;           // argmax, first-occurrence ties
      double mx = fmax(lb0, lb1);
      double se = exp(lb0 - mx) + exp(lb1 - mx);
      double lpb = ((bi ? lb1 : lb0) - mx) - log(se);
      st[97] = (float)bi;
      st[98] = (float)(lpg_sh + lpb);
    }
    __syncthreads();   // bar7: full state + outputs ready

    if (tid < STATE) {
      float v = st[tid];
      out[((size_t)t * NB + n) * STATE + tid] = v;
      if (t == T_STEPS - 1) out[out_final + (size_t)n * STATE + tid] = v;
    }
    xf_cur = xf_next;
    // no barrier needed: next writers to st/s_arr sit behind bar1/bar2 of next iter
  }
}

// ---------------- launcher ----------------
extern "C" void kernel_launch(void* const* d_in, const int* in_sizes, int n_in,
                              void* d_out, int out_size, void* d_ws, size_t ws_size,
                              hipStream_t stream) {
  const float* inp = (const float*)d_in[0];
  const float* hx  = (const float*)d_in[1];
  const float* Wf  = (const float*)d_in[2];
  const float* bf  = (const float*)d_in[3];
  const float* Wih = (const float*)d_in[4];
  const float* bih = (const float*)d_in[5];
  const float* bhh = (const float*)d_in[6];
  const float* Wc  = (const float*)d_in[7];
  const float* bc  = (const float*)d_in[8];
  const float* Wl  = (const float*)d_in[9];
  const float* bl  = (const float*)d_in[10];
  const float* Wpi = (const float*)d_in[11];
  const float* bpi = (const float*)d_in[12];
  const float* Wb  = (const float*)d_in[13];
  const float* bb  = (const float*)d_in[14];
  float* out = (float*)d_out;

  // ws layout: doubles first (8B alignment), then floats
  double* Xb = (double*)d_ws;                             // 16384*2  doubles
  double* Gg = Xb + (size_t)16384 * 2;                    // 128*128*90 doubles
  double* Gb = Gg + (size_t)T_STEPS * NB * NG;            // 128*128*2 doubles
  float*  Wt = (float*)(Gb + (size_t)T_STEPS * NB * 2);   // 4096*68 floats
  float*  Xf = Wt + (size_t)4096 * 68;                    // 16384*64 floats
  // total ws use: ~17.6 MB

  k_transpose<<<(66 * 4096) / 256, 256, 0, stream>>>(Wf, Wb, Wt);
  k_gemm<<<256, 256, 0, stream>>>(inp, Wt, Xf, Xb);
  k_noise<<<T_STEPS, 256, 0, stream>>>(Gg, Gb);
  k_scan<<<NB, 256, 0, stream>>>(inp, hx, Wf, bf, Wih, bih, bhh, Wc, bc, Wl, bl,
                                 Wpi, bpi, Wb, bb, Xf, Xb, Gg, Gb, out);
}

// Round 3
// 1383.349 us; speedup vs baseline: 1.1575x; 1.1575x over previous
//
#include <hip/hip_runtime.h>
#include <stdint.h>
#include <math.h>

// Problem constants (from reference)
#define T_STEPS 128
#define NB      128
#define HID     64
#define CONVOUT 4096
#define NSUB    5
#define SUBSZ   14      // A+B+C = 5+3+6
#define NG      90      // A*B*C
#define STATE   99
#define DIN     4111    // CONVOUT + 3*NSUB
#define WFCOLS  4125    // CONVOUT + 2*SUBSZ + 1
#define WBCOLS  4110    // CONVOUT + SUBSZ
#define NROWS   (T_STEPS * NB)   // 16384

// ---------------- Threefry-2x32 (JAX-compatible) ----------------
__device__ __forceinline__ void tf2x32(unsigned k0, unsigned k1,
                                       unsigned x0, unsigned x1,
                                       unsigned &o0, unsigned &o1) {
  unsigned K0 = k0, K1 = k1, K2 = k0 ^ k1 ^ 0x1BD11BDAu;
  x0 += K0; x1 += K1;
  const int R0[4] = {13, 15, 26, 6};
  const int R1[4] = {17, 29, 16, 24};
  #pragma unroll
  for (int j = 0; j < 4; ++j) { x0 += x1; x1 = (x1 << R0[j]) | (x1 >> (32 - R0[j])); x1 ^= x0; }
  x0 += K1; x1 += K2 + 1u;
  #pragma unroll
  for (int j = 0; j < 4; ++j) { x0 += x1; x1 = (x1 << R1[j]) | (x1 >> (32 - R1[j])); x1 ^= x0; }
  x0 += K2; x1 += K0 + 2u;
  #pragma unroll
  for (int j = 0; j < 4; ++j) { x0 += x1; x1 = (x1 << R0[j]) | (x1 >> (32 - R0[j])); x1 ^= x0; }
  x0 += K0; x1 += K1 + 3u;
  #pragma unroll
  for (int j = 0; j < 4; ++j) { x0 += x1; x1 = (x1 << R1[j]) | (x1 >> (32 - R1[j])); x1 ^= x0; }
  x0 += K1; x1 += K2 + 4u;
  #pragma unroll
  for (int j = 0; j < 4; ++j) { x0 += x1; x1 = (x1 << R0[j]) | (x1 >> (32 - R0[j])); x1 ^= x0; }
  x0 += K2; x1 += K0 + 5u;
  o0 = x0; o1 = x1;
}

__device__ __forceinline__ double bits_to_gumbel_d(unsigned bits) {
  float f = __uint_as_float((bits >> 9) | 0x3f800000u) - 1.0f;   // exact in f32
  const double tiny = (double)1.17549435e-38f;
  double u = fmax(tiny, (double)f + tiny);
  return -log(-log(u));
}

__device__ __forceinline__ float rlane(float v, int l) {
  return __int_as_float(__builtin_amdgcn_readlane(__float_as_int(v), l));
}

// Barrier that waits LDS only (lgkmcnt(0)) — does NOT drain vmcnt, so global
// prefetch loads / fire-and-forget stores stay in flight across it.
// simm16 = vmcnt 63 (no wait: [3:0]=0xF,[15:14]=0x3), expcnt 7, lgkmcnt 0.
__device__ __forceinline__ void bar_lds() {
  __asm__ volatile("" ::: "memory");
  __builtin_amdgcn_s_waitcnt(0xC07F);
  __builtin_amdgcn_s_barrier();
  __asm__ volatile("" ::: "memory");
}

// ---------------- K0: pack/transpose weights ----------------
__global__ void k_transpose(const float* __restrict__ Wf, const float* __restrict__ Wb,
                            float* __restrict__ Wt) {
  int idx = blockIdx.x * 256 + threadIdx.x;     // < 66*4096
  int c = idx >> 12;                            // 0..65
  int k = idx & 4095;
  float v = (c < 64) ? Wf[(size_t)c * WFCOLS + k] : Wb[(size_t)(c - 64) * WBCOLS + k];
  Wt[(size_t)k * 68 + c] = v;
}

// ---------------- K1: big GEMM, k-split 4 -> partials ----------------
// 1024 blocks x 256 thr = 4 waves/SIMD occupancy. block = (row-group, k-quarter).
__global__ __launch_bounds__(256, 4) void k_gemm(const float* __restrict__ inp,
                                                 const float* __restrict__ Wt,
                                                 float* __restrict__ Pf,
                                                 double* __restrict__ Pd) {
  __shared__ float  red[2][64][65];
  __shared__ double redd[2][64][2];
  int tid = threadIdx.x;
  int r = tid & 63;
  int w = __builtin_amdgcn_readfirstlane(tid >> 6);
  int rg = blockIdx.x >> 2, kq = blockIdx.x & 3;
  int row = rg * 64 + r;
  int kbase = kq * 1024 + w * 256;
  const float* xrow  = inp + (size_t)row * DIN + kbase;
  const float* wbase = Wt + (size_t)kbase * 68;

  float acc[64];
  #pragma unroll
  for (int c = 0; c < 64; ++c) acc[c] = 0.f;
  double ad0 = 0.0, ad1 = 0.0;

  for (int k = 0; k < 256; ++k) {
    float x = xrow[k];
    const float* wp = wbase + (size_t)k * 68;   // wave-uniform -> scalar loads
    #pragma unroll
    for (int c = 0; c < 64; ++c) acc[c] = fmaf(x, wp[c], acc[c]);
    double xd = (double)x;
    ad0 = fma(xd, (double)wp[64], ad0);
    ad1 = fma(xd, (double)wp[65], ad1);
  }
  if (w >= 2) {
    float* d = red[w - 2][r];
    #pragma unroll
    for (int c = 0; c < 64; ++c) d[c] = acc[c];
    redd[w - 2][r][0] = ad0; redd[w - 2][r][1] = ad1;
  }
  __syncthreads();
  if (w < 2) {
    const float* s = red[w][r];
    #pragma unroll
    for (int c = 0; c < 64; ++c) acc[c] += s[c];
    ad0 += redd[w][r][0]; ad1 += redd[w][r][1];
  }
  __syncthreads();
  if (w == 1) {
    float* d = red[0][r];
    #pragma unroll
    for (int c = 0; c < 64; ++c) d[c] = acc[c];
    redd[0][r][0] = ad0; redd[0][r][1] = ad1;
  }
  __syncthreads();
  if (w == 0) {
    const float* s = red[0][r];
    #pragma unroll
    for (int c = 0; c < 64; ++c) acc[c] += s[c];
    ad0 += redd[0][r][0]; ad1 += redd[0][r][1];
    float* po = Pf + (size_t)kq * NROWS * 64 + (size_t)row * 64;
    #pragma unroll
    for (int c = 0; c < 64; ++c) po[c] = acc[c];
    Pd[(size_t)kq * NROWS * 2 + (size_t)row * 2 + 0] = ad0;
    Pd[(size_t)kq * NROWS * 2 + (size_t)row * 2 + 1] = ad1;
  }
}

// ---------------- K1b: reduce the 4 k-quarter partials ----------------
__global__ void k_reduce(const float* __restrict__ Pf, const double* __restrict__ Pd,
                         float* __restrict__ Xf, double* __restrict__ Xb) {
  size_t gid = (size_t)blockIdx.x * 256 + threadIdx.x;
  const size_t NF = (size_t)NROWS * 64;
  if (gid < NF) {
    Xf[gid] = (Pf[gid] + Pf[NF + gid]) + (Pf[2 * NF + gid] + Pf[3 * NF + gid]);
  } else if (gid < NF + (size_t)NROWS * 2) {
    size_t j = gid - NF;
    const size_t ND = (size_t)NROWS * 2;
    Xb[j] = (Pd[j] + Pd[ND + j]) + (Pd[2 * ND + j] + Pd[3 * ND + j]);
  }
}

// ---------------- K2: gumbel noise (JAX partitionable threefry), FP64 ----------------
__global__ void k_noise(double* __restrict__ Gg, double* __restrict__ Gb) {
  int t = blockIdx.x, tid = threadIdx.x;
  unsigned a, b, k1a, k1b, k2a, k2b, o0, o1;
  tf2x32(0u, 42u, 0u, (unsigned)t, a, b);      // keys[t] = split(key(42),128)[t]
  tf2x32(a, b, 0u, 0u, k1a, k1b);              // k1
  tf2x32(a, b, 0u, 1u, k2a, k2b);              // k2
  for (int i = tid; i < NB * NG; i += 256) {
    tf2x32(k1a, k1b, 0u, (unsigned)i, o0, o1);
    Gg[(size_t)t * NB * NG + i] = bits_to_gumbel_d(o0 ^ o1);
  }
  {
    int i = tid;                               // NB*2 == 256 == blockDim
    tf2x32(k2a, k2b, 0u, (unsigned)i, o0, o1);
    Gb[(size_t)t * NB * 2 + i] = bits_to_gumbel_d(o0 ^ o1);
  }
}

// ---------------- K3: sequential scan, one block per batch row ----------------
// wave0 owns all state; waves 1-3 compute only gi. 2 LDS-only barriers/step.
__global__ __launch_bounds__(256) void k_scan(
    const float* __restrict__ inp, const float* __restrict__ hx,
    const float* __restrict__ Wf, const float* __restrict__ bf,
    const float* __restrict__ Wih, const float* __restrict__ bih,
    const float* __restrict__ bhh, const float* __restrict__ Wc,
    const float* __restrict__ bc, const float* __restrict__ Wl,
    const float* __restrict__ bl, const float* __restrict__ Wpi,
    const float* __restrict__ bpi, const float* __restrict__ Wb,
    const float* __restrict__ bb,
    const float* __restrict__ Xf, const double* __restrict__ Xb,
    const double* __restrict__ Gg, const double* __restrict__ Gb,
    float* __restrict__ lgst, float* __restrict__ lbst,
    int* __restrict__ gidxst, int* __restrict__ bidxst,
    float* __restrict__ out) {
  const int n = blockIdx.x;
  const int tid = threadIdx.x;
  const int lane = tid & 63;
  const int w = __builtin_amdgcn_readfirstlane(tid >> 6);

  __shared__ float s_lds[64], h_lds[64], gi_lds[192];
  __shared__ int nz_sh;

  // ---- waves 1..3: register-resident Wih rows ----
  float wih_r[128];
  float bih_r = 0.f;
  if (w != 0) {
    int m = tid - 64;
    #pragma unroll
    for (int k = 0; k < 128; ++k) wih_r[k] = Wih[(size_t)m * 128 + k];
    bih_r = bih[m];
  }

  // ---- wave0 state & constants ----
  float wfs[29], wpi0[78], wpi1[78], mtr[5];
  float bf_r = 0, bhr_r = 0, bhz_r = 0, bhn_r = 0;
  float wc0 = 0, wc1 = 0, wl0 = 0, wl1 = 0, wl2 = 0;
  float bl0 = 0, bl1 = 0, bl2 = 0, bc0 = 0, bpi0 = 0, bpi1 = 0;
  float wbs0 = 0, wbs1 = 0;
  float hreg = 0.f, rgbp = 0.f, xf = 0.f;
  double S0 = 0.0, S1 = 0.0, bb0d = 0.0, bb1d = 0.0;
  double gum0 = 0.0, gum1 = 0.0, xb0 = 0.0, xb1 = 0.0, gb0 = 0.0, gb1 = 0.0;
  int dsto = -1;

  if (tid == 0) nz_sh = 0;
  __syncthreads();
  {
    int any = 0;
    const float4* h4 = (const float4*)hx;
    for (int i = tid; i < (NB * STATE) / 4; i += 256) {
      float4 v = h4[i];
      any |= (v.x != 0.f) | (v.y != 0.f) | (v.z != 0.f) | (v.w != 0.f);
    }
    if (any) nz_sh = 1;
  }
  if (w == 0) {
    #pragma unroll
    for (int k = 0; k < 29; ++k) wfs[k] = Wf[(size_t)lane * WFCOLS + CONVOUT + k];
    #pragma unroll
    for (int k = 0; k < 78; ++k) wpi0[k] = Wpi[(size_t)lane * 78 + k];
    bpi0 = bpi[lane];
    if (lane < 26) {
      #pragma unroll
      for (int k = 0; k < 78; ++k) wpi1[k] = Wpi[(size_t)(64 + lane) * 78 + k];
      bpi1 = bpi[64 + lane];
    }
    bf_r = bf[lane];
    bhr_r = bhh[lane]; bhz_r = bhh[64 + lane]; bhn_r = bhh[128 + lane];
    wc0 = Wc[lane]; wc1 = Wc[64 + lane]; bc0 = bc[0];
    wl0 = Wl[lane]; wl1 = Wl[64 + lane]; wl2 = Wl[128 + lane];
    bl0 = bl[0]; bl1 = bl[1]; bl2 = bl[2];
    bb0d = (double)bb[0]; bb1d = (double)bb[1];
    if (lane < 14) { wbs0 = Wb[CONVOUT + lane]; wbs1 = Wb[(size_t)WBCOLS + CONVOUT + lane]; }
    const float* r0 = inp + (size_t)n * DIN + CONVOUT;
    #pragma unroll
    for (int k = 0; k < 5; ++k) {
      int ttv = (int)r0[k], cntv = (int)r0[5 + k] - 1, objv = (int)r0[10 + k];
      float v = 0.f;
      if (lane < 5)       v = (lane == ttv) ? 1.f : 0.f;
      else if (lane < 8)  v = ((lane - 5) == cntv) ? 1.f : 0.f;
      else if (lane < 14) v = ((lane - 8) == objv) ? 1.f : 0.f;
      mtr[k] = v;
    }
    // packed state layout: lanes 0-13 r, 14-27 g, 28 b, 29-33 p
    int src = -1;
    if (lane < 14)       { dsto = 5 + lane;          src = dsto; }
    else if (lane < 28)  { dsto = 83 + (lane - 14);  src = dsto; }
    else if (lane == 28) { dsto = 97;                src = 97; }
    else if (lane < 34)  { dsto = lane - 29;         src = dsto; }
    rgbp = (src >= 0) ? hx[(size_t)n * STATE + src] : 0.f;
    hreg = hx[(size_t)n * STATE + 19 + lane];
  }
  __syncthreads();   // nz_sh ready
  if (w == 0) {
    if (nz_sh == 0) {   // new episode (hx all zero): p[0]=1, r=g=M[:,0]
      const float* r0 = inp + (size_t)n * DIN + CONVOUT;
      int tt0 = (int)r0[0], cnt0 = (int)r0[5] - 1, obj0 = (int)r0[10];
      if (lane == 29) rgbp = 1.f;
      else if (lane < 14) rgbp = mtr[0];
      else if (lane >= 14 && lane < 28) {
        int j = lane - 14;
        rgbp = (j < 5) ? ((j == tt0) ? 1.f : 0.f)
             : (j < 8) ? (((j - 5) == cnt0) ? 1.f : 0.f)
                       : (((j - 8) == obj0) ? 1.f : 0.f);
      }
    }
    // S recurrence init: S = dot(g0, Wbs) fp64
    #pragma unroll
    for (int j = 0; j < 14; ++j) {
      double gv = (double)rlane(rgbp, 14 + j);
      S0 += gv * (double)rlane(wbs0, j);
      S1 += gv * (double)rlane(wbs1, j);
    }
    h_lds[lane] = hreg;    // publish h(0)
    // t=0 data
    gum0 = Gg[(size_t)n * NG + lane];
    gum1 = (lane < 26) ? Gg[(size_t)n * NG + 64 + lane] : 0.0;
    xf = Xf[(size_t)n * 64 + lane];
    xb0 = Xb[(size_t)n * 2 + 0]; xb1 = Xb[(size_t)n * 2 + 1];
    gb0 = Gb[(size_t)n * 2 + 0]; gb1 = Gb[(size_t)n * 2 + 1];
  }
  __syncthreads();

  const size_t outF = (size_t)T_STEPS * NB * STATE;

  #pragma unroll 1
  for (int t = 0; t < T_STEPS; ++t) {
    float sv_own = 0.f, cg = 0.f, accR0 = 0.f, accR1 = 0.f;
    double cgd = 0.0;

    if (w == 0) {
      // s = xf + bf + Wf_state . [r,g,b]   (rgb packed in lanes 0..28)
      float acc = xf + bf_r;
      #pragma unroll
      for (int k = 0; k < 29; ++k) acc = fmaf(wfs[k], rlane(rgbp, k), acc);
      sv_own = acc;
      s_lds[lane] = acc;
    }
    bar_lds();   // ---- bar_s: s (and h from prev step) published ----

    if (w == 0) {
      // ---- slack work (runs concurrent with waves1-3 gi) ----
      float p0 = wl0 * hreg, p1 = wl1 * hreg, p2 = wl2 * hreg;
      float cga = fmaf(wc1, hreg, wc0 * sv_own);
      #pragma unroll
      for (int off = 32; off; off >>= 1) {
        p0 += __shfl_xor(p0, off, 64);
        p1 += __shfl_xor(p1, off, 64);
        p2 += __shfl_xor(p2, off, 64);
        cga += __shfl_xor(cga, off, 64);
      }
      p0 += bl0; p1 += bl1; p2 += bl2;
      float mx = fmaxf(p0, fmaxf(p1, p2));
      float e0 = expf(p0 - mx), e1 = expf(p1 - mx), e2 = expf(p2 - mx);
      float se = e0 + e1 + e2;
      float l0 = e0 / se, l1 = e1 / se, l2 = e2 / se;
      cg = 1.f / (1.f + expf(-(cga + bc0)));
      cgd = (double)cg;
      // pconv: p values are uniform via readlane
      float pv0 = rlane(rgbp, 29), pv1 = rlane(rgbp, 30), pv2 = rlane(rgbp, 31);
      float pv3 = rlane(rgbp, 32), pv4 = rlane(rgbp, 33);
      float pc0 = pv0 * l1 + pv1 * l2;
      float pc1 = pv0 * l0 + pv1 * l1 + pv2 * l2;
      float pc2 = pv1 * l0 + pv2 * l1 + pv3 * l2;
      float pc3 = pv2 * l0 + pv3 * l1 + pv4 * l2;
      float pc4 = pv3 * l0 + pv4 * l1;
      // p update (lanes 29-33), r update (lanes 0-13)
      if (lane >= 29 && lane < 34) {
        float pcl = (lane == 29) ? pc0 : (lane == 30) ? pc1 : (lane == 31) ? pc2
                  : (lane == 32) ? pc3 : pc4;
        rgbp = cg * pcl + (1.f - cg) * rgbp;
      }
      if (lane < 14) {
        float rn = pc0 * mtr[0] + pc1 * mtr[1] + pc2 * mtr[2] + pc3 * mtr[3] + pc4 * mtr[4];
        rgbp = cg * rn + (1.f - cg) * rgbp;
      }
      // lg r-part (uses new r)
      #pragma unroll
      for (int k = 0; k < 14; ++k) {
        float rv = rlane(rgbp, k);
        accR0 = fmaf(wpi0[64 + k], rv, accR0);
        accR1 = fmaf(wpi1[64 + k], rv, accR1);
      }
    } else {
      // ---- waves 1..3: gi = Wih . [s, h] + bih ----
      float sv = s_lds[lane];
      float hv = h_lds[lane];
      float acc = bih_r;
      #pragma unroll
      for (int k = 0; k < 64; ++k) acc = fmaf(wih_r[k], rlane(sv, k), acc);
      #pragma unroll
      for (int k = 0; k < 64; ++k) acc = fmaf(wih_r[64 + k], rlane(hv, k), acc);
      gi_lds[tid - 64] = acc;
    }
    bar_lds();   // ---- bar_gi ----

    if (w == 0) {
      // prefetch t+1 inputs now; they drain at next bar_s (~full step of slack)
      int tn = (t + 1 < T_STEPS) ? t + 1 : t;
      double gum0n = Gg[(size_t)tn * NB * NG + (size_t)n * NG + lane];
      double gum1n = (lane < 26) ? Gg[(size_t)tn * NB * NG + (size_t)n * NG + 64 + lane] : 0.0;
      float xfn = Xf[((size_t)tn * NB + n) * 64 + lane];
      double xb0n = Xb[((size_t)tn * NB + n) * 2 + 0];
      double xb1n = Xb[((size_t)tn * NB + n) * 2 + 1];
      double gb0n = Gb[((size_t)tn * NB + n) * 2 + 0];
      double gb1n = Gb[((size_t)tn * NB + n) * 2 + 1];

      // gates + h update
      float g0 = gi_lds[lane], g1 = gi_lds[64 + lane], g2 = gi_lds[128 + lane];
      float rg = 1.f / (1.f + expf(-(g0 + bhr_r)));
      float z  = 1.f / (1.f + expf(-(g1 + bhz_r)));
      float nn = tanhf(g2 + rg * bhn_r);
      float hnew = (1.f - z) * nn;
      hreg = cg * hnew + (1.f - cg) * hreg;

      // lg (fp32 fast path)
      float a0 = bpi0 + accR0, a1 = bpi1 + accR1;
      #pragma unroll
      for (int k = 0; k < 64; ++k) {
        float hv2 = rlane(hreg, k);
        a0 = fmaf(wpi0[k], hv2, a0);
        a1 = fmaf(wpi1[k], hv2, a1);
      }
      const float NEGINF = -3.0e38f;
      float vb0 = (float)(gum0 + (double)a0);
      float vb1 = (lane < 26) ? (float)(gum1 + (double)a1) : NEGINF;
      // butterfly argmax carrying (m1, idx, m2) for margin check
      float m1, m2; int idx;
      if (vb1 > vb0) { m1 = vb1; idx = lane + 64; m2 = vb0; }
      else           { m1 = vb0; idx = lane;      m2 = vb1; }
      #pragma unroll
      for (int off = 32; off; off >>= 1) {
        float o1 = __shfl_xor(m1, off, 64);
        int   oi = __shfl_xor(idx, off, 64);
        float o2 = __shfl_xor(m2, off, 64);
        bool take = (o1 > m1) || (o1 == m1 && oi < idx);
        float base2 = take ? m1 : m2;
        float oth   = take ? o2 : o1;
        m2 = fmaxf(base2, oth);
        if (take) { m1 = o1; idx = oi; }
      }
      int gidx = idx;
      if (m1 - m2 < 3e-5f) {
        // rare fp64 slow path: exact recompute, weights from global
        double e0d = (double)bpi0;
        double e1d = (lane < 26) ? (double)bpi1 : -1.0e300;
        #pragma unroll 1
        for (int k = 0; k < 64; ++k) {
          double hv2 = (double)rlane(hreg, k);
          e0d = fma((double)Wpi[(size_t)lane * 78 + k], hv2, e0d);
          if (lane < 26) e1d = fma((double)Wpi[(size_t)(64 + lane) * 78 + k], hv2, e1d);
        }
        #pragma unroll 1
        for (int k = 0; k < 14; ++k) {
          double rv = (double)rlane(rgbp, k);
          e0d = fma((double)Wpi[(size_t)lane * 78 + 64 + k], rv, e0d);
          if (lane < 26) e1d = fma((double)Wpi[(size_t)(64 + lane) * 78 + 64 + k], rv, e1d);
        }
        double kk0 = e0d + gum0;
        double kk1 = (lane < 26) ? e1d + gum1 : -1.0e300;
        double d1; int di;
        if (kk1 > kk0) { d1 = kk1; di = lane + 64; } else { d1 = kk0; di = lane; }
        #pragma unroll
        for (int off = 32; off; off >>= 1) {
          double od = __shfl_xor(d1, off, 64);
          int    oi = __shfl_xor(di, off, 64);
          if (od > d1 || (od == d1 && oi < di)) { d1 = od; di = oi; }
        }
        gidx = di;
      }
      // g update from sampled embedding
      int t1 = gidx / 18, rem = gidx - t1 * 18;
      int b1 = rem / 6, c1 = rem - b1 * 6;
      if (lane >= 14 && lane < 28) {
        int j = lane - 14;
        float ge = (j < 5) ? ((j == t1) ? 1.f : 0.f)
                 : (j < 8) ? (((j - 5) == b1) ? 1.f : 0.f)
                           : (((j - 8) == c1) ? 1.f : 0.f);
        rgbp = cg * ge + (1.f - cg) * rgbp;
      }
      // b sample via fp64 scalar recurrence S = dot(g, Wbs)
      double u0 = (double)rlane(wbs0, t1) + (double)rlane(wbs0, 5 + b1) + (double)rlane(wbs0, 8 + c1);
      double u1 = (double)rlane(wbs1, t1) + (double)rlane(wbs1, 5 + b1) + (double)rlane(wbs1, 8 + c1);
      S0 = cgd * u0 + (1.0 - cgd) * S0;
      S1 = cgd * u1 + (1.0 - cgd) * S1;
      double lb0 = xb0 + bb0d + S0;
      double lb1 = xb1 + bb1d + S1;
      int bi = ((lb1 + gb1) > (lb0 + gb0)) ? 1 : 0;
      if (lane == 28) rgbp = (float)bi;

      // stores (fire-and-forget; barriers never drain vmcnt)
      size_t rn = (size_t)t * NB + n;
      float* ob = out + rn * STATE;
      if (dsto >= 0) ob[dsto] = rgbp;
      ob[19 + lane] = hreg;
      lgst[rn * NG + lane] = a0;
      if (lane < 26) lgst[rn * NG + 64 + lane] = a1;
      if (lane == 0) {
        lbst[rn * 2 + 0] = (float)lb0; lbst[rn * 2 + 1] = (float)lb1;
        gidxst[rn] = gidx; bidxst[rn] = bi;
      }
      if (t == T_STEPS - 1) {
        float* of = out + outF + (size_t)n * STATE;
        if (dsto >= 0) of[dsto] = rgbp;
        of[19 + lane] = hreg;
      }
      // publish h for next step, rotate prefetched data
      h_lds[lane] = hreg;
      gum0 = gum0n; gum1 = gum1n; xf = xfn;
      xb0 = xb0n; xb1 = xb1n; gb0 = gb0n; gb1 = gb1n;
    }
  }
}

// ---------------- K4: deferred log-prob (fp32, fully parallel) ----------------
__global__ __launch_bounds__(256) void k_lp(const float* __restrict__ lgst,
                                            const float* __restrict__ lbst,
                                            const int* __restrict__ gidxst,
                                            const int* __restrict__ bidxst,
                                            float* __restrict__ out) {
  int tid = threadIdx.x, lane = tid & 63, w = tid >> 6;
  size_t rn = (size_t)blockIdx.x * 4 + w;   // < 16384
  const float* lg = lgst + rn * NG;
  float v0 = lg[lane];
  float v1 = (lane < 26) ? lg[64 + lane] : -3.0e38f;
  float ml = fmaxf(v0, v1);
  #pragma unroll
  for (int off = 32; off; off >>= 1) ml = fmaxf(ml, __shfl_xor(ml, off, 64));
  float e = expf(v0 - ml) + ((lane < 26) ? expf(v1 - ml) : 0.f);
  #pragma unroll
  for (int off = 32; off; off >>= 1) e += __shfl_xor(e, off, 64);
  int gi = gidxst[rn];
  float lpg = (lg[gi] - ml) - logf(e);
  float lb0 = lbst[rn * 2 + 0], lb1 = lbst[rn * 2 + 1];
  int bi = bidxst[rn];
  float mx = fmaxf(lb0, lb1);
  float seb = expf(lb0 - mx) + expf(lb1 - mx);
  float lpb = ((bi ? lb1 : lb0) - mx) - logf(seb);
  if (lane == 0) {
    int t = (int)(rn / NB), n = (int)(rn % NB);
    float lp = lpg + lpb;
    out[rn * STATE + 98] = lp;
    if (t == T_STEPS - 1) out[(size_t)T_STEPS * NB * STATE + (size_t)n * STATE + 98] = lp;
  }
}

// ---------------- launcher ----------------
extern "C" void kernel_launch(void* const* d_in, const int* in_sizes, int n_in,
                              void* d_out, int out_size, void* d_ws, size_t ws_size,
                              hipStream_t stream) {
  const float* inp = (const float*)d_in[0];
  const float* hx  = (const float*)d_in[1];
  const float* Wf  = (const float*)d_in[2];
  const float* bf  = (const float*)d_in[3];
  const float* Wih = (const float*)d_in[4];
  const float* bih = (const float*)d_in[5];
  const float* bhh = (const float*)d_in[6];
  const float* Wc  = (const float*)d_in[7];
  const float* bc  = (const float*)d_in[8];
  const float* Wl  = (const float*)d_in[9];
  const float* bl  = (const float*)d_in[10];
  const float* Wpi = (const float*)d_in[11];
  const float* bpi = (const float*)d_in[12];
  const float* Wb  = (const float*)d_in[13];
  const float* bb  = (const float*)d_in[14];
  float* out = (float*)d_out;

  // ws layout (doubles first for alignment), total ~35.5 MB:
  double* Gg = (double*)d_ws;                       // 128*128*90
  double* Gb = Gg + (size_t)T_STEPS * NB * NG;      // 128*128*2
  double* Xb = Gb + (size_t)T_STEPS * NB * 2;       // 16384*2
  double* Pd = Xb + (size_t)NROWS * 2;              // 4*16384*2
  float*  Wt = (float*)(Pd + (size_t)4 * NROWS * 2);// 4096*68
  float*  Xf = Wt + (size_t)4096 * 68;              // 16384*64
  float*  Pf = Xf + (size_t)NROWS * 64;             // 4*16384*64 (16.8 MB)
  // aliased onto Pf (consumed by k_reduce before k_scan writes these):
  float*  lgst = Pf;                                // 16384*90
  float*  lbst = lgst + (size_t)NROWS * NG;         // 16384*2
  int*    gidxst = (int*)(lbst + (size_t)NROWS * 2);// 16384
  int*    bidxst = gidxst + NROWS;                  // 16384

  k_transpose<<<(66 * 4096) / 256, 256, 0, stream>>>(Wf, Wb, Wt);
  k_gemm<<<1024, 256, 0, stream>>>(inp, Wt, Pf, Pd);
  {
    size_t tot = (size_t)NROWS * 64 + (size_t)NROWS * 2;
    k_reduce<<<(int)((tot + 255) / 256), 256, 0, stream>>>(Pf, Pd, Xf, Xb);
  }
  k_noise<<<T_STEPS, 256, 0, stream>>>(Gg, Gb);
  k_scan<<<NB, 256, 0, stream>>>(inp, hx, Wf, bf, Wih, bih, bhh, Wc, bc, Wl, bl,
                                 Wpi, bpi, Wb, bb, Xf, Xb, Gg, Gb,
                                 lgst, lbst, gidxst, bidxst, out);
  k_lp<<<NROWS / 4, 256, 0, stream>>>(lgst, lbst, gidxst, bidxst, out);
}